// Round 1
// 258.171 us; speedup vs baseline: 1.1784x; 1.1784x over previous
//
#include <hip/hip_runtime.h>
#include <hip/hip_bf16.h>
#include <math.h>

#define BDIM 4
#define VDIM 8
#define NDIM 256
#define CDIM 768
#define HDIM 12
#define DHE  64
#define C3   (3*CDIM)
#define ROWS (BDIM*VDIM*NDIM)
#define KEYS (VDIM*NDIM)   // 2048

typedef __attribute__((ext_vector_type(8))) short short8;   // 8 bf16 = 4 VGPR
typedef __attribute__((ext_vector_type(4))) float float4v;  // MFMA acc

__device__ inline unsigned short f2bf(float f) {
    unsigned int u = __builtin_bit_cast(unsigned int, f);
    u += 0x7fffu + ((u >> 16) & 1u);   // RNE
    return (unsigned short)(u >> 16);
}

// packed f32x2 -> bf16x2 in a uint (low half = a, high half = b), RNE
__device__ __forceinline__ unsigned int pk2(float a, float b) {
    return (unsigned int)f2bf(a) | ((unsigned int)f2bf(b) << 16);
}

// 8 fp32 (two float4) -> uint4 of 8 bf16
__device__ __forceinline__ uint4 pk8(float4 a, float4 b) {
    uint4 r;
    r.x = pk2(a.x, a.y); r.y = pk2(a.z, a.w);
    r.z = pk2(b.x, b.y); r.w = pk2(b.z, b.w);
    return r;
}

// async 16B global -> LDS (wave-uniform base + lane*16; lane-order == LDS order)
__device__ __forceinline__ void gld_lds16(const unsigned short* g, unsigned short* l) {
    __builtin_amdgcn_global_load_lds(
        (const __attribute__((address_space(1))) void*)g,
        (__attribute__((address_space(3))) void*)l, 16, 0, 0);
}

// ---------------------------------------------------------------------------
// One-shot fp32 -> bf16 pre-cast of feats, w_qkv, w_out (memory-bound ~9us).
// This removes the in-GEMM-loop pk8 packing that made staging VALU-bound
// (VALUBusy 27%, MfmaUtil 9%) and unlocks global_load_lds staging.
// ---------------------------------------------------------------------------
#define NA8 786432   // 8192*768/8
#define NW8 221184   // 2304*768/8
#define NO8 73728    //  768*768/8

__global__ __launch_bounds__(256) void cast_bf16_all(
    const float* __restrict__ fA, const float* __restrict__ fW,
    const float* __restrict__ fO,
    unsigned short* __restrict__ bA, unsigned short* __restrict__ bW,
    unsigned short* __restrict__ bO)
{
    const int gid = blockIdx.x * 256 + threadIdx.x;
    const float* src;
    unsigned short* dst;
    int idx;
    if (gid < NA8)            { src = fA; dst = bA; idx = gid; }
    else if (gid < NA8 + NW8) { src = fW; dst = bW; idx = gid - NA8; }
    else                      { src = fO; dst = bO; idx = gid - NA8 - NW8; }
    const float4* p = (const float4*)(src + (size_t)idx * 8);
    *(uint4*)(dst + (size_t)idx * 8) = pk8(p[0], p[1]);
}

// ---------------------------------------------------------------------------
// Fused QKV GEMM, m97 step-3 structure: bf16 inputs, global_load_lds width-16
// direct into linear [128][32] LDS tiles (no VGPR round-trip, no ds_write,
// no pack VALU in the loop). V col-blocks (col0 >= 1536) still write the
// TRANSPOSED vT buffer directly and skip qkv.
// ---------------------------------------------------------------------------
__global__ __launch_bounds__(256) void gemm_qkv_mfma(
    const unsigned short* __restrict__ A,    // feats bf16 [8192][768]
    const unsigned short* __restrict__ W,    // w_qkv bf16 [2304][768]
    const float* __restrict__ bias,
    unsigned short* __restrict__ out,        // qkv [8192][2304] bf16 (Q,K only)
    unsigned short* __restrict__ vT)         // [4][12][64][2048] bf16
{
    __shared__ __attribute__((aligned(16))) unsigned short As[128][32];
    __shared__ __attribute__((aligned(16))) unsigned short Ws[128][32];
    const int t = threadIdx.x;
    const int wave = t >> 6, lane = t & 63;
    const int m = lane & 15, quad = lane >> 4;
    const int wr = (wave >> 1) * 64, wc = (wave & 1) * 64;
    const int row0 = blockIdx.y * 128, col0 = blockIdx.x * 128;

    // staging: thread t owns row (t>>2), k-chunk (t&3)*8 -> LDS byte t*16
    const int sr = t >> 2, sk = (t & 3) * 8;
    const unsigned short* ag = &A[(size_t)(row0 + sr) * CDIM + sk];
    const unsigned short* wg = &W[(size_t)(col0 + sr) * CDIM + sk];
    unsigned short* la0 = &As[sr][sk];
    unsigned short* la1 = &As[64 + sr][sk];
    unsigned short* lw0 = &Ws[sr][sk];
    unsigned short* lw1 = &Ws[64 + sr][sk];

    float4v acc[4][4] = {};

    for (int k0 = 0; k0 < CDIM; k0 += 32) {
        gld_lds16(ag + k0, la0);
        gld_lds16(ag + (size_t)64 * CDIM + k0, la1);
        gld_lds16(wg + k0, lw0);
        gld_lds16(wg + (size_t)64 * CDIM + k0, lw1);
        __syncthreads();   // compiler emits vmcnt(0) drain before s_barrier
        short8 a[4], b[4];
        #pragma unroll
        for (int rt = 0; rt < 4; rt++)
            a[rt] = *(const short8*)&As[wr + rt * 16 + m][quad * 8];
        #pragma unroll
        for (int ct = 0; ct < 4; ct++)
            b[ct] = *(const short8*)&Ws[wc + ct * 16 + m][quad * 8];
        #pragma unroll
        for (int rt = 0; rt < 4; rt++)
            #pragma unroll
            for (int ct = 0; ct < 4; ct++)
                acc[rt][ct] = __builtin_amdgcn_mfma_f32_16x16x32_bf16(
                    a[rt], b[ct], acc[rt][ct], 0, 0, 0);
        __syncthreads();
    }

    if (col0 < 2 * CDIM) {
        // Q/K epilogue -> qkv
        #pragma unroll
        for (int ct = 0; ct < 4; ct++) {
            const int col = col0 + wc + ct * 16 + m;
            const float bv = bias[col];
            #pragma unroll
            for (int rt = 0; rt < 4; rt++) {
                const size_t row = (size_t)row0 + wr + rt * 16 + quad * 4;
                #pragma unroll
                for (int r = 0; r < 4; r++)
                    out[(row + r) * C3 + col] = f2bf(acc[rt][ct][r] + bv);
            }
        }
    } else {
        // V epilogue -> transposed vT (4 consecutive keys per lane -> 8B)
        #pragma unroll
        for (int ct = 0; ct < 4; ct++) {
            const int vcol = col0 + wc + ct * 16 + m - 2 * CDIM;
            const int h = vcol >> 6, d = vcol & 63;
            const float bv = bias[col0 + wc + ct * 16 + m];
            #pragma unroll
            for (int rt = 0; rt < 4; rt++) {
                const int row = row0 + wr + rt * 16 + quad * 4;
                const int bidx = row >> 11, key = row & 2047;
                ushort4 pkv;
                pkv.x = f2bf(acc[rt][ct][0] + bv);
                pkv.y = f2bf(acc[rt][ct][1] + bv);
                pkv.z = f2bf(acc[rt][ct][2] + bv);
                pkv.w = f2bf(acc[rt][ct][3] + bv);
                *(ushort4*)&vT[((size_t)(bidx * HDIM + h) * DHE + d) * KEYS + key] = pkv;
            }
        }
    }
}

// ---------------------------------------------------------------------------
// MFMA flash attention, round 10 = R5/R6 two-barrier structure (known-best)
// with the S^T softmax path. UNCHANGED this round.
// ---------------------------------------------------------------------------
__global__ __launch_bounds__(256, 3) void attn_mfma(
    const unsigned short* __restrict__ qkv,  // [8192][2304] bf16 (Q,K)
    const unsigned short* __restrict__ vT,   // [4][12][64][2048] bf16
    const int* __restrict__ is_ref,
    unsigned short* __restrict__ ctx)        // [8192][768] bf16
{
    const int gid = blockIdx.x;
    const int xcd = gid & 7;
    const int slot = gid >> 3;               // 0..95
    const int grp = xcd * 6 + (slot >> 4);   // 0..47 = (b,h)
    const int sub = slot & 15;               // 0..15 = (half,v)
    const int b = grp / HDIM, h = grp % HDIM;
    const int v = sub & 7, half = sub >> 3;

    const int t = threadIdx.x, wave = t >> 6, lane = t & 63;
    const int m = lane & 15, quad = lane >> 4;
    const int n0 = half * 128 + wave * 32;

    __shared__ unsigned short Ks[128][64];   // [key][dim], dg' = dg ^ (key&7)
    __shared__ unsigned short Vs[64][128];   // [dim][key], kg' = kg ^ (dim&15)
    __shared__ unsigned short Ps[4][32][72]; // [wave][query][64-key half]

    const int my_ref = is_ref[b * VDIM + v];
    unsigned amask = 0;
    #pragma unroll
    for (int w = 0; w < VDIM; w++)
        if ((is_ref[b * VDIM + w] != 0) ^ (my_ref != 0)) amask |= 1u << w;
    const int nChunks = 2 * __popc(amask);

    const float c1 = 0.18033688f;  // 0.125 * log2(e)

    // Q B-frags: B[n=query=m][k=quad*8+j], two 32-dim K-steps
    short8 aq[2][2];
    #pragma unroll
    for (int qt = 0; qt < 2; qt++) {
        const size_t row = (size_t)((b * VDIM + v) * NDIM) + n0 + qt * 16 + m;
        #pragma unroll
        for (int ks = 0; ks < 2; ks++)
            aq[qt][ks] = *(const short8*)&qkv[row * C3 + h * DHE + ks * 32 + quad * 8];
    }

    float rs[2] = {0.f, 0.f};     // per-lane l partial, query = qt*16 + m
    float4v O[2][4] = {};

    // staging thread coords
    const int k_key = t >> 3, k_dg = t & 7;    // key = i*32 + k_key
    const int v_dim = t >> 4, v_kg = t & 15;   // dim = i*16 + v_dim

    const unsigned short* vTb = vT + (size_t)(b * HDIM + h) * DHE * KEYS;

    uint4 kreg[4], vreg[4];
    unsigned rem = amask;
    int wcur = __builtin_ffs((int)rem) - 1;

    if (nChunks > 0) {
        const unsigned short* kb =
            qkv + (size_t)((b * VDIM + wcur) * NDIM) * C3 + CDIM + h * DHE;
        #pragma unroll
        for (int i = 0; i < 4; i++)
            kreg[i] = *(const uint4*)&kb[(size_t)(i * 32 + k_key) * C3 + k_dg * 8];
        #pragma unroll
        for (int i = 0; i < 4; i++)
            vreg[i] = *(const uint4*)&vTb[(size_t)(i * 16 + v_dim) * KEYS
                                          + wcur * NDIM + v_kg * 8];
    }

    for (int ci = 0; ci < nChunks; ci++) {
        __syncthreads();   // prev chunk's LDS reads complete
        #pragma unroll
        for (int i = 0; i < 4; i++)
            *(uint4*)&Ks[i * 32 + k_key][(k_dg ^ (k_key & 7)) * 8] = kreg[i];
        #pragma unroll
        for (int i = 0; i < 4; i++)
            *(uint4*)&Vs[i * 16 + v_dim][(v_kg ^ v_dim) * 8] = vreg[i];

        if (ci + 1 < nChunks) {   // prefetch next chunk into regs
            int wn, m0n;
            if ((ci & 1) == 0) { wn = wcur; m0n = 128; }
            else {
                unsigned r2 = rem & (rem - 1);
                wn = __builtin_ffs((int)r2) - 1; m0n = 0;
            }
            const unsigned short* kb =
                qkv + (size_t)((b * VDIM + wn) * NDIM + m0n) * C3 + CDIM + h * DHE;
            #pragma unroll
            for (int i = 0; i < 4; i++)
                kreg[i] = *(const uint4*)&kb[(size_t)(i * 32 + k_key) * C3 + k_dg * 8];
            #pragma unroll
            for (int i = 0; i < 4; i++)
                vreg[i] = *(const uint4*)&vTb[(size_t)(i * 16 + v_dim) * KEYS
                                              + wn * NDIM + m0n + v_kg * 8];
        }
        __syncthreads();   // LDS tiles visible

        // two 64-key halves: S^T tiles -> packed Ps, then PV for that half
        #pragma unroll
        for (int hk = 0; hk < 2; hk++) {
            #pragma unroll
            for (int kt = 0; kt < 4; kt++) {
                const int nt = hk * 4 + kt;
                // A-frag = K (lane m = key within tile), same reads as before
                const short8 bk0 = *(const short8*)&Ks[nt * 16 + m][(quad ^ (m & 7)) * 8];
                const short8 bk1 = *(const short8*)&Ks[nt * 16 + m][((4 + quad) ^ (m & 7)) * 8];
                #pragma unroll
                for (int qt = 0; qt < 2; qt++) {
                    float4v s = {};
                    s = __builtin_amdgcn_mfma_f32_16x16x32_bf16(bk0, aq[qt][0], s, 0, 0, 0);
                    s = __builtin_amdgcn_mfma_f32_16x16x32_bf16(bk1, aq[qt][1], s, 0, 0, 0);
                    // s[r]: key = nt*16 + quad*4 + r, query = qt*16 + m
                    const float p0 = __builtin_amdgcn_exp2f(s[0] * c1);
                    const float p1 = __builtin_amdgcn_exp2f(s[1] * c1);
                    const float p2 = __builtin_amdgcn_exp2f(s[2] * c1);
                    const float p3 = __builtin_amdgcn_exp2f(s[3] * c1);
                    rs[qt] += (p0 + p1) + (p2 + p3);
                    uint2 pw;
                    pw.x = pk2(p0, p1);
                    pw.y = pk2(p2, p3);
                    *(uint2*)&Ps[wave][qt * 16 + m][kt * 16 + quad * 4] = pw;
                }
            }
            #pragma unroll
            for (int kk = 0; kk < 2; kk++) {
                const short8 ap0 = *(const short8*)&Ps[wave][m][kk * 32 + quad * 8];
                const short8 ap1 = *(const short8*)&Ps[wave][16 + m][kk * 32 + quad * 8];
                #pragma unroll
                for (int ct = 0; ct < 4; ct++) {
                    const short8 bv = *(const short8*)&Vs[ct * 16 + m]
                        [((hk * 8 + kk * 4 + quad) ^ m) * 8];
                    O[0][ct] = __builtin_amdgcn_mfma_f32_16x16x32_bf16(ap0, bv, O[0][ct], 0, 0, 0);
                    O[1][ct] = __builtin_amdgcn_mfma_f32_16x16x32_bf16(ap1, bv, O[1][ct], 0, 0, 0);
                }
            }
        }
        if (ci & 1) { rem &= rem - 1; wcur = __builtin_ffs((int)rem) - 1; }
    }

    // final: reduce l across the 4 quad-copies, broadcast to O rows, write
    #pragma unroll
    for (int qt = 0; qt < 2; qt++) {
        float x = rs[qt];
        x += __shfl_xor(x, 16, 64);
        x += __shfl_xor(x, 32, 64);
        const float inv = (x > 0.f) ? 1.f / x : 0.f;   // query = qt*16 + m
        float invq[4];
        #pragma unroll
        for (int r = 0; r < 4; r++)
            invq[r] = __shfl(inv, quad * 4 + r, 64);   // query = qt*16+quad*4+r
        const size_t rowg = (size_t)((b * VDIM + v) * NDIM) + n0 + qt * 16 + quad * 4;
        #pragma unroll
        for (int ct = 0; ct < 4; ct++)
            #pragma unroll
            for (int r = 0; r < 4; r++)
                ctx[(rowg + r) * CDIM + h * DHE + ct * 16 + m] = f2bf(O[qt][ct][r] * invq[r]);
    }
}

// ---------------------------------------------------------------------------
// Out-proj GEMM, same global_load_lds staging (A already bf16, W pre-cast);
// fp32 out + passthrough.
// ---------------------------------------------------------------------------
__global__ __launch_bounds__(256) void gemm_out_mfma(
    const unsigned short* __restrict__ A,   // ctx_b [8192][768] bf16
    const unsigned short* __restrict__ W,   // w_out bf16 [768][768]
    const float* __restrict__ bias,
    const float* __restrict__ feats,
    const int* __restrict__ is_ref,
    float* __restrict__ out)                // [8192][768] fp32
{
    __shared__ __attribute__((aligned(16))) unsigned short As[128][32];
    __shared__ __attribute__((aligned(16))) unsigned short Ws[128][32];
    const int t = threadIdx.x;
    const int wave = t >> 6, lane = t & 63;
    const int m = lane & 15, quad = lane >> 4;
    const int wr = (wave >> 1) * 64, wc = (wave & 1) * 64;
    const int row0 = blockIdx.y * 128, col0 = blockIdx.x * 128;

    const int sr = t >> 2, sk = (t & 3) * 8;
    const unsigned short* ag = &A[(size_t)(row0 + sr) * CDIM + sk];
    const unsigned short* wg = &W[(size_t)(col0 + sr) * CDIM + sk];
    unsigned short* la0 = &As[sr][sk];
    unsigned short* la1 = &As[64 + sr][sk];
    unsigned short* lw0 = &Ws[sr][sk];
    unsigned short* lw1 = &Ws[64 + sr][sk];

    float4v acc[4][4] = {};

    for (int k0 = 0; k0 < CDIM; k0 += 32) {
        gld_lds16(ag + k0, la0);
        gld_lds16(ag + (size_t)64 * CDIM + k0, la1);
        gld_lds16(wg + k0, lw0);
        gld_lds16(wg + (size_t)64 * CDIM + k0, lw1);
        __syncthreads();
        short8 a[4], b[4];
        #pragma unroll
        for (int rt = 0; rt < 4; rt++)
            a[rt] = *(const short8*)&As[wr + rt * 16 + m][quad * 8];
        #pragma unroll
        for (int ct = 0; ct < 4; ct++)
            b[ct] = *(const short8*)&Ws[wc + ct * 16 + m][quad * 8];
        #pragma unroll
        for (int rt = 0; rt < 4; rt++)
            #pragma unroll
            for (int ct = 0; ct < 4; ct++)
                acc[rt][ct] = __builtin_amdgcn_mfma_f32_16x16x32_bf16(
                    a[rt], b[ct], acc[rt][ct], 0, 0, 0);
        __syncthreads();
    }

    const int bidx = row0 / (VDIM * NDIM);
    const int vidx = (row0 / NDIM) % VDIM;
    const int my = is_ref[bidx * VDIM + vidx];
    bool has = false;
    #pragma unroll
    for (int w = 0; w < VDIM; w++) has = has || (is_ref[bidx * VDIM + w] != my);

    #pragma unroll
    for (int ct = 0; ct < 4; ct++) {
        const int col = col0 + wc + ct * 16 + m;
        const float bv = bias[col];
        #pragma unroll
        for (int rt = 0; rt < 4; rt++) {
            const size_t row = (size_t)row0 + wr + rt * 16 + quad * 4;
            #pragma unroll
            for (int r = 0; r < 4; r++) {
                float o = acc[rt][ct][r] + bv;
                if (!has) o = feats[(row + r) * CDIM + col];
                out[(row + r) * CDIM + col] = o;
            }
        }
    }
}

extern "C" void kernel_launch(void* const* d_in, const int* in_sizes, int n_in,
                              void* d_out, int out_size, void* d_ws, size_t ws_size,
                              hipStream_t stream) {
    const float* feats = (const float*)d_in[0];
    const int*   is_ref = (const int*)d_in[1];
    const float* w_qkv = (const float*)d_in[2];
    const float* b_qkv = (const float*)d_in[3];
    const float* w_out = (const float*)d_in[4];
    const float* b_out = (const float*)d_in[5];
    float* out = (float*)d_out;

    unsigned short* qkv_b = (unsigned short*)d_ws;                 // 8192x2304
    unsigned short* vT    = qkv_b + (size_t)ROWS * C3;             // 4x12x64x2048
    unsigned short* ctx_b = vT + (size_t)BDIM * HDIM * DHE * KEYS; // 8192x768
    unsigned short* A_bf  = ctx_b + (size_t)ROWS * CDIM;           // 8192x768
    unsigned short* Wq_bf = A_bf + (size_t)ROWS * CDIM;            // 2304x768
    unsigned short* Wo_bf = Wq_bf + (size_t)C3 * CDIM;             // 768x768

    cast_bf16_all<<<dim3((NA8 + NW8 + NO8) / 256), 256, 0, stream>>>(
        feats, w_qkv, w_out, A_bf, Wq_bf, Wo_bf);

    dim3 g1(C3 / 128, ROWS / 128);                                 // 18 x 64
    gemm_qkv_mfma<<<g1, 256, 0, stream>>>(A_bf, Wq_bf, b_qkv, qkv_b, vT);

    attn_mfma<<<dim3(768), 256, 0, stream>>>(qkv_b, vT, is_ref, ctx_b);

    dim3 g3(CDIM / 128, ROWS / 128);                               // 6 x 64
    gemm_out_mfma<<<g3, 256, 0, stream>>>(ctx_b, Wo_bf, b_out, feats, is_ref, out);
    (void)in_sizes; (void)n_in; (void)out_size; (void)ws_size;
}

// Round 2
// 255.753 us; speedup vs baseline: 1.1895x; 1.0095x over previous
//
#include <hip/hip_runtime.h>
#include <hip/hip_bf16.h>
#include <math.h>

#define BDIM 4
#define VDIM 8
#define NDIM 256
#define CDIM 768
#define HDIM 12
#define DHE  64
#define C3   (3*CDIM)
#define ROWS (BDIM*VDIM*NDIM)
#define KEYS (VDIM*NDIM)   // 2048

typedef __attribute__((ext_vector_type(8))) short short8;   // 8 bf16 = 4 VGPR
typedef __attribute__((ext_vector_type(4))) float float4v;  // MFMA acc

__device__ inline unsigned short f2bf(float f) {
    unsigned int u = __builtin_bit_cast(unsigned int, f);
    u += 0x7fffu + ((u >> 16) & 1u);   // RNE
    return (unsigned short)(u >> 16);
}

// packed f32x2 -> bf16x2 in a uint (low half = a, high half = b), RNE
__device__ __forceinline__ unsigned int pk2(float a, float b) {
    return (unsigned int)f2bf(a) | ((unsigned int)f2bf(b) << 16);
}

// 8 fp32 (two float4) -> uint4 of 8 bf16
__device__ __forceinline__ uint4 pk8(float4 a, float4 b) {
    uint4 r;
    r.x = pk2(a.x, a.y); r.y = pk2(a.z, a.w);
    r.z = pk2(b.x, b.y); r.w = pk2(b.z, b.w);
    return r;
}

// async 16B global -> LDS (wave-uniform base + lane*16; lane-order == LDS order)
__device__ __forceinline__ void gld_lds16(const unsigned short* g, unsigned short* l) {
    __builtin_amdgcn_global_load_lds(
        (const __attribute__((address_space(1))) void*)g,
        (__attribute__((address_space(3))) void*)l, 16, 0, 0);
}

// ---------------------------------------------------------------------------
// One-shot fp32 -> bf16 pre-cast of feats, w_qkv, w_out (memory-bound ~9us).
// ---------------------------------------------------------------------------
#define NA8 786432   // 8192*768/8
#define NW8 221184   // 2304*768/8
#define NO8 73728    //  768*768/8

__global__ __launch_bounds__(256) void cast_bf16_all(
    const float* __restrict__ fA, const float* __restrict__ fW,
    const float* __restrict__ fO,
    unsigned short* __restrict__ bA, unsigned short* __restrict__ bW,
    unsigned short* __restrict__ bO)
{
    const int gid = blockIdx.x * 256 + threadIdx.x;
    const float* src;
    unsigned short* dst;
    int idx;
    if (gid < NA8)            { src = fA; dst = bA; idx = gid; }
    else if (gid < NA8 + NW8) { src = fW; dst = bW; idx = gid - NA8; }
    else                      { src = fO; dst = bO; idx = gid - NA8 - NW8; }
    const float4* p = (const float4*)(src + (size_t)idx * 8);
    *(uint4*)(dst + (size_t)idx * 8) = pk8(p[0], p[1]);
}

// ---------------------------------------------------------------------------
// Fused QKV GEMM, m97 step-3 structure: bf16 inputs, global_load_lds width-16
// direct into linear [128][32] LDS tiles. V col-blocks (col0 >= 1536) write
// the TRANSPOSED vT buffer directly and skip qkv.
// ---------------------------------------------------------------------------
__global__ __launch_bounds__(256) void gemm_qkv_mfma(
    const unsigned short* __restrict__ A,    // feats bf16 [8192][768]
    const unsigned short* __restrict__ W,    // w_qkv bf16 [2304][768]
    const float* __restrict__ bias,
    unsigned short* __restrict__ out,        // qkv [8192][2304] bf16 (Q,K only)
    unsigned short* __restrict__ vT)         // [4][12][64][2048] bf16
{
    __shared__ __attribute__((aligned(16))) unsigned short As[128][32];
    __shared__ __attribute__((aligned(16))) unsigned short Ws[128][32];
    const int t = threadIdx.x;
    const int wave = t >> 6, lane = t & 63;
    const int m = lane & 15, quad = lane >> 4;
    const int wr = (wave >> 1) * 64, wc = (wave & 1) * 64;
    const int row0 = blockIdx.y * 128, col0 = blockIdx.x * 128;

    // staging: thread t owns row (t>>2), k-chunk (t&3)*8 -> LDS byte t*16
    const int sr = t >> 2, sk = (t & 3) * 8;
    const unsigned short* ag = &A[(size_t)(row0 + sr) * CDIM + sk];
    const unsigned short* wg = &W[(size_t)(col0 + sr) * CDIM + sk];
    unsigned short* la0 = &As[sr][sk];
    unsigned short* la1 = &As[64 + sr][sk];
    unsigned short* lw0 = &Ws[sr][sk];
    unsigned short* lw1 = &Ws[64 + sr][sk];

    float4v acc[4][4] = {};

    for (int k0 = 0; k0 < CDIM; k0 += 32) {
        gld_lds16(ag + k0, la0);
        gld_lds16(ag + (size_t)64 * CDIM + k0, la1);
        gld_lds16(wg + k0, lw0);
        gld_lds16(wg + (size_t)64 * CDIM + k0, lw1);
        __syncthreads();
        short8 a[4], b[4];
        #pragma unroll
        for (int rt = 0; rt < 4; rt++)
            a[rt] = *(const short8*)&As[wr + rt * 16 + m][quad * 8];
        #pragma unroll
        for (int ct = 0; ct < 4; ct++)
            b[ct] = *(const short8*)&Ws[wc + ct * 16 + m][quad * 8];
        #pragma unroll
        for (int rt = 0; rt < 4; rt++)
            #pragma unroll
            for (int ct = 0; ct < 4; ct++)
                acc[rt][ct] = __builtin_amdgcn_mfma_f32_16x16x32_bf16(
                    a[rt], b[ct], acc[rt][ct], 0, 0, 0);
        __syncthreads();
    }

    if (col0 < 2 * CDIM) {
        // Q/K epilogue -> qkv
        #pragma unroll
        for (int ct = 0; ct < 4; ct++) {
            const int col = col0 + wc + ct * 16 + m;
            const float bv = bias[col];
            #pragma unroll
            for (int rt = 0; rt < 4; rt++) {
                const size_t row = (size_t)row0 + wr + rt * 16 + quad * 4;
                #pragma unroll
                for (int r = 0; r < 4; r++)
                    out[(row + r) * C3 + col] = f2bf(acc[rt][ct][r] + bv);
            }
        }
    } else {
        // V epilogue -> transposed vT (4 consecutive keys per lane -> 8B)
        #pragma unroll
        for (int ct = 0; ct < 4; ct++) {
            const int vcol = col0 + wc + ct * 16 + m - 2 * CDIM;
            const int h = vcol >> 6, d = vcol & 63;
            const float bv = bias[col0 + wc + ct * 16 + m];
            #pragma unroll
            for (int rt = 0; rt < 4; rt++) {
                const int row = row0 + wr + rt * 16 + quad * 4;
                const int bidx = row >> 11, key = row & 2047;
                ushort4 pkv;
                pkv.x = f2bf(acc[rt][ct][0] + bv);
                pkv.y = f2bf(acc[rt][ct][1] + bv);
                pkv.z = f2bf(acc[rt][ct][2] + bv);
                pkv.w = f2bf(acc[rt][ct][3] + bv);
                *(ushort4*)&vT[((size_t)(bidx * HDIM + h) * DHE + d) * KEYS + key] = pkv;
            }
        }
    }
}

// ---------------------------------------------------------------------------
// MFMA flash attention. R2 change: block->task remap for LOAD BALANCE.
// Old: grp = xcd*6 + slot>>4 put 6 consecutive (b,h) (i.e. ~one batch b) on
// each XCD; per-(b,h) work = 4r(8-r) chunks varies 0..64 with r = #refs(b),
// so whole XCDs got 2-3x the work of others -> Occupancy 20% vs 37.5% cap.
// New: grp = gid % 48, sub = gid / 48. Dispatcher round-robins gid across
// XCDs, so XCD x still sees exactly 6 distinct (b,h) ({x, x+8, ...} mod 48,
// same L2 footprint ~3MB) but spanning all 4 batches -> balanced work.
// ---------------------------------------------------------------------------
__global__ __launch_bounds__(256, 3) void attn_mfma(
    const unsigned short* __restrict__ qkv,  // [8192][2304] bf16 (Q,K)
    const unsigned short* __restrict__ vT,   // [4][12][64][2048] bf16
    const int* __restrict__ is_ref,
    unsigned short* __restrict__ ctx)        // [8192][768] bf16
{
    const int gid = blockIdx.x;
    const int grp = gid % 48;                // (b,h) — consecutive gids differ
    const int sub = gid / 48;                // 0..15 = (half,v)
    const int b = grp / HDIM, h = grp % HDIM;
    const int v = sub & 7, half = sub >> 3;

    const int t = threadIdx.x, wave = t >> 6, lane = t & 63;
    const int m = lane & 15, quad = lane >> 4;
    const int n0 = half * 128 + wave * 32;

    __shared__ unsigned short Ks[128][64];   // [key][dim], dg' = dg ^ (key&7)
    __shared__ unsigned short Vs[64][128];   // [dim][key], kg' = kg ^ (dim&15)
    __shared__ unsigned short Ps[4][32][72]; // [wave][query][64-key half]

    const int my_ref = is_ref[b * VDIM + v];
    unsigned amask = 0;
    #pragma unroll
    for (int w = 0; w < VDIM; w++)
        if ((is_ref[b * VDIM + w] != 0) ^ (my_ref != 0)) amask |= 1u << w;
    const int nChunks = 2 * __popc(amask);

    const float c1 = 0.18033688f;  // 0.125 * log2(e)

    // Q B-frags: B[n=query=m][k=quad*8+j], two 32-dim K-steps
    short8 aq[2][2];
    #pragma unroll
    for (int qt = 0; qt < 2; qt++) {
        const size_t row = (size_t)((b * VDIM + v) * NDIM) + n0 + qt * 16 + m;
        #pragma unroll
        for (int ks = 0; ks < 2; ks++)
            aq[qt][ks] = *(const short8*)&qkv[row * C3 + h * DHE + ks * 32 + quad * 8];
    }

    float rs[2] = {0.f, 0.f};     // per-lane l partial, query = qt*16 + m
    float4v O[2][4] = {};

    // staging thread coords
    const int k_key = t >> 3, k_dg = t & 7;    // key = i*32 + k_key
    const int v_dim = t >> 4, v_kg = t & 15;   // dim = i*16 + v_dim

    const unsigned short* vTb = vT + (size_t)(b * HDIM + h) * DHE * KEYS;

    uint4 kreg[4], vreg[4];
    unsigned rem = amask;
    int wcur = __builtin_ffs((int)rem) - 1;

    if (nChunks > 0) {
        const unsigned short* kb =
            qkv + (size_t)((b * VDIM + wcur) * NDIM) * C3 + CDIM + h * DHE;
        #pragma unroll
        for (int i = 0; i < 4; i++)
            kreg[i] = *(const uint4*)&kb[(size_t)(i * 32 + k_key) * C3 + k_dg * 8];
        #pragma unroll
        for (int i = 0; i < 4; i++)
            vreg[i] = *(const uint4*)&vTb[(size_t)(i * 16 + v_dim) * KEYS
                                          + wcur * NDIM + v_kg * 8];
    }

    for (int ci = 0; ci < nChunks; ci++) {
        __syncthreads();   // prev chunk's LDS reads complete
        #pragma unroll
        for (int i = 0; i < 4; i++)
            *(uint4*)&Ks[i * 32 + k_key][(k_dg ^ (k_key & 7)) * 8] = kreg[i];
        #pragma unroll
        for (int i = 0; i < 4; i++)
            *(uint4*)&Vs[i * 16 + v_dim][(v_kg ^ v_dim) * 8] = vreg[i];

        if (ci + 1 < nChunks) {   // prefetch next chunk into regs
            int wn, m0n;
            if ((ci & 1) == 0) { wn = wcur; m0n = 128; }
            else {
                unsigned r2 = rem & (rem - 1);
                wn = __builtin_ffs((int)r2) - 1; m0n = 0;
            }
            const unsigned short* kb =
                qkv + (size_t)((b * VDIM + wn) * NDIM + m0n) * C3 + CDIM + h * DHE;
            #pragma unroll
            for (int i = 0; i < 4; i++)
                kreg[i] = *(const uint4*)&kb[(size_t)(i * 32 + k_key) * C3 + k_dg * 8];
            #pragma unroll
            for (int i = 0; i < 4; i++)
                vreg[i] = *(const uint4*)&vTb[(size_t)(i * 16 + v_dim) * KEYS
                                              + wn * NDIM + m0n + v_kg * 8];
        }
        __syncthreads();   // LDS tiles visible

        // two 64-key halves: S^T tiles -> packed Ps, then PV for that half
        #pragma unroll
        for (int hk = 0; hk < 2; hk++) {
            #pragma unroll
            for (int kt = 0; kt < 4; kt++) {
                const int nt = hk * 4 + kt;
                // A-frag = K (lane m = key within tile)
                const short8 bk0 = *(const short8*)&Ks[nt * 16 + m][(quad ^ (m & 7)) * 8];
                const short8 bk1 = *(const short8*)&Ks[nt * 16 + m][((4 + quad) ^ (m & 7)) * 8];
                #pragma unroll
                for (int qt = 0; qt < 2; qt++) {
                    float4v s = {};
                    s = __builtin_amdgcn_mfma_f32_16x16x32_bf16(bk0, aq[qt][0], s, 0, 0, 0);
                    s = __builtin_amdgcn_mfma_f32_16x16x32_bf16(bk1, aq[qt][1], s, 0, 0, 0);
                    // s[r]: key = nt*16 + quad*4 + r, query = qt*16 + m
                    const float p0 = __builtin_amdgcn_exp2f(s[0] * c1);
                    const float p1 = __builtin_amdgcn_exp2f(s[1] * c1);
                    const float p2 = __builtin_amdgcn_exp2f(s[2] * c1);
                    const float p3 = __builtin_amdgcn_exp2f(s[3] * c1);
                    rs[qt] += (p0 + p1) + (p2 + p3);
                    uint2 pw;
                    pw.x = pk2(p0, p1);
                    pw.y = pk2(p2, p3);
                    *(uint2*)&Ps[wave][qt * 16 + m][kt * 16 + quad * 4] = pw;
                }
            }
            #pragma unroll
            for (int kk = 0; kk < 2; kk++) {
                const short8 ap0 = *(const short8*)&Ps[wave][m][kk * 32 + quad * 8];
                const short8 ap1 = *(const short8*)&Ps[wave][16 + m][kk * 32 + quad * 8];
                #pragma unroll
                for (int ct = 0; ct < 4; ct++) {
                    const short8 bv = *(const short8*)&Vs[ct * 16 + m]
                        [((hk * 8 + kk * 4 + quad) ^ m) * 8];
                    O[0][ct] = __builtin_amdgcn_mfma_f32_16x16x32_bf16(ap0, bv, O[0][ct], 0, 0, 0);
                    O[1][ct] = __builtin_amdgcn_mfma_f32_16x16x32_bf16(ap1, bv, O[1][ct], 0, 0, 0);
                }
            }
        }
        if (ci & 1) { rem &= rem - 1; wcur = __builtin_ffs((int)rem) - 1; }
    }

    // final: reduce l across the 4 quad-copies, broadcast to O rows, write
    #pragma unroll
    for (int qt = 0; qt < 2; qt++) {
        float x = rs[qt];
        x += __shfl_xor(x, 16, 64);
        x += __shfl_xor(x, 32, 64);
        const float inv = (x > 0.f) ? 1.f / x : 0.f;   // query = qt*16 + m
        float invq[4];
        #pragma unroll
        for (int r = 0; r < 4; r++)
            invq[r] = __shfl(inv, quad * 4 + r, 64);   // query = qt*16+quad*4+r
        const size_t rowg = (size_t)((b * VDIM + v) * NDIM) + n0 + qt * 16 + quad * 4;
        #pragma unroll
        for (int ct = 0; ct < 4; ct++)
            #pragma unroll
            for (int r = 0; r < 4; r++)
                ctx[(rowg + r) * CDIM + h * DHE + ct * 16 + m] = f2bf(O[qt][ct][r] * invq[r]);
    }
}

// ---------------------------------------------------------------------------
// Out-proj GEMM, global_load_lds staging; fp32 out + passthrough.
// ---------------------------------------------------------------------------
__global__ __launch_bounds__(256) void gemm_out_mfma(
    const unsigned short* __restrict__ A,   // ctx_b [8192][768] bf16
    const unsigned short* __restrict__ W,   // w_out bf16 [768][768]
    const float* __restrict__ bias,
    const float* __restrict__ feats,
    const int* __restrict__ is_ref,
    float* __restrict__ out)                // [8192][768] fp32
{
    __shared__ __attribute__((aligned(16))) unsigned short As[128][32];
    __shared__ __attribute__((aligned(16))) unsigned short Ws[128][32];
    const int t = threadIdx.x;
    const int wave = t >> 6, lane = t & 63;
    const int m = lane & 15, quad = lane >> 4;
    const int wr = (wave >> 1) * 64, wc = (wave & 1) * 64;
    const int row0 = blockIdx.y * 128, col0 = blockIdx.x * 128;

    const int sr = t >> 2, sk = (t & 3) * 8;
    const unsigned short* ag = &A[(size_t)(row0 + sr) * CDIM + sk];
    const unsigned short* wg = &W[(size_t)(col0 + sr) * CDIM + sk];
    unsigned short* la0 = &As[sr][sk];
    unsigned short* la1 = &As[64 + sr][sk];
    unsigned short* lw0 = &Ws[sr][sk];
    unsigned short* lw1 = &Ws[64 + sr][sk];

    float4v acc[4][4] = {};

    for (int k0 = 0; k0 < CDIM; k0 += 32) {
        gld_lds16(ag + k0, la0);
        gld_lds16(ag + (size_t)64 * CDIM + k0, la1);
        gld_lds16(wg + k0, lw0);
        gld_lds16(wg + (size_t)64 * CDIM + k0, lw1);
        __syncthreads();
        short8 a[4], b[4];
        #pragma unroll
        for (int rt = 0; rt < 4; rt++)
            a[rt] = *(const short8*)&As[wr + rt * 16 + m][quad * 8];
        #pragma unroll
        for (int ct = 0; ct < 4; ct++)
            b[ct] = *(const short8*)&Ws[wc + ct * 16 + m][quad * 8];
        #pragma unroll
        for (int rt = 0; rt < 4; rt++)
            #pragma unroll
            for (int ct = 0; ct < 4; ct++)
                acc[rt][ct] = __builtin_amdgcn_mfma_f32_16x16x32_bf16(
                    a[rt], b[ct], acc[rt][ct], 0, 0, 0);
        __syncthreads();
    }

    const int bidx = row0 / (VDIM * NDIM);
    const int vidx = (row0 / NDIM) % VDIM;
    const int my = is_ref[bidx * VDIM + vidx];
    bool has = false;
    #pragma unroll
    for (int w = 0; w < VDIM; w++) has = has || (is_ref[bidx * VDIM + w] != my);

    #pragma unroll
    for (int ct = 0; ct < 4; ct++) {
        const int col = col0 + wc + ct * 16 + m;
        const float bv = bias[col];
        #pragma unroll
        for (int rt = 0; rt < 4; rt++) {
            const size_t row = (size_t)row0 + wr + rt * 16 + quad * 4;
            #pragma unroll
            for (int r = 0; r < 4; r++) {
                float o = acc[rt][ct][r] + bv;
                if (!has) o = feats[(row + r) * CDIM + col];
                out[(row + r) * CDIM + col] = o;
            }
        }
    }
}

extern "C" void kernel_launch(void* const* d_in, const int* in_sizes, int n_in,
                              void* d_out, int out_size, void* d_ws, size_t ws_size,
                              hipStream_t stream) {
    const float* feats = (const float*)d_in[0];
    const int*   is_ref = (const int*)d_in[1];
    const float* w_qkv = (const float*)d_in[2];
    const float* b_qkv = (const float*)d_in[3];
    const float* w_out = (const float*)d_in[4];
    const float* b_out = (const float*)d_in[5];
    float* out = (float*)d_out;

    unsigned short* qkv_b = (unsigned short*)d_ws;                 // 8192x2304
    unsigned short* vT    = qkv_b + (size_t)ROWS * C3;             // 4x12x64x2048
    unsigned short* ctx_b = vT + (size_t)BDIM * HDIM * DHE * KEYS; // 8192x768
    unsigned short* A_bf  = ctx_b + (size_t)ROWS * CDIM;           // 8192x768
    unsigned short* Wq_bf = A_bf + (size_t)ROWS * CDIM;            // 2304x768
    unsigned short* Wo_bf = Wq_bf + (size_t)C3 * CDIM;             // 768x768

    cast_bf16_all<<<dim3((NA8 + NW8 + NO8) / 256), 256, 0, stream>>>(
        feats, w_qkv, w_out, A_bf, Wq_bf, Wo_bf);

    dim3 g1(C3 / 128, ROWS / 128);                                 // 18 x 64
    gemm_qkv_mfma<<<g1, 256, 0, stream>>>(A_bf, Wq_bf, b_qkv, qkv_b, vT);

    attn_mfma<<<dim3(768), 256, 0, stream>>>(qkv_b, vT, is_ref, ctx_b);

    dim3 g3(CDIM / 128, ROWS / 128);                               // 6 x 64
    gemm_out_mfma<<<g3, 256, 0, stream>>>(ctx_b, Wo_bf, b_out, feats, is_ref, out);
    (void)in_sizes; (void)n_in; (void)out_size; (void)ws_size;
}